// Round 1
// baseline (6668.096 us; speedup 1.0000x reference)
//
#include <hip/hip_runtime.h>
#include <math.h>

#define D 512
#define BM 64
#define BJ 32
#define BK 32
#define ASTRIDE 68    // 64 + 4 pad (keeps float4 align, 2-way max on writes)
#define BSTRIDE 168   // 160 + 8 pad (keeps float4 align, kills 8-way write conflict)

__device__ __forceinline__ float sigmoidf_(float x) { return 1.0f / (1.0f + expf(-x)); }

// One tree level: iou/f GEMM + LSTM gate epilogue, fully fused.
// Layouts: Hc/Cc = [64][nc][512] (children, node-local), Hp/Cp = [64][np][512].
// Row m = b*np + p. A-row = concat(h_left, h_right) = contiguous 1024 floats
// (children 2p, 2p+1 are adjacent node slots).
// LEAF: A-row gathered from embedding[tokens], c_children = 0.
template<bool LEAF>
__global__ __launch_bounds__(256)
void level_kernel(const float* __restrict__ Hc, const float* __restrict__ Cc,
                  const int* __restrict__ tokens, const float* __restrict__ emb,
                  const float* __restrict__ W_iou, const float* __restrict__ b_iou,
                  const float* __restrict__ W_f,  const float* __restrict__ b_f,
                  float* __restrict__ Hp, float* __restrict__ Cp,
                  int np, int lgnp)
{
    __shared__ float As[BK][ASTRIDE];   // transposed: As[k][row]
    __shared__ float Bs[BK][BSTRIDE];   // Bs[k][gate*32 + j]

    const int tid = threadIdx.x;
    const int m0  = blockIdx.x * BM;
    const int j0  = blockIdx.y * BJ;
    const int nc  = np * 2;

    // compute roles: tx = j within tile, ty = row-group (8 rows each)
    const int tx = tid & 31;
    const int ty = tid >> 5;

    float acc[8][5];
#pragma unroll
    for (int r = 0; r < 8; r++)
#pragma unroll
        for (int g = 0; g < 5; g++) acc[r][g] = 0.f;

    // A staging role: rA = row (0..63), tA = k-chunk (0..3), covers k tA*8..tA*8+7
    const int rA = tid & 63, tA = tid >> 6;
    const int mA = m0 + rA;
    const int bA = mA >> lgnp;
    const int pA = mA & (np - 1);

    const float* arow = nullptr;
    long tokL = 0, tokR = 0;
    if (LEAF) {
        tokL = tokens[bA * 1024 + 2 * pA];
        tokR = tokens[bA * 1024 + 2 * pA + 1];
    } else {
        arow = Hc + ((long)(bA * nc + 2 * pA)) * D;
    }

    // B staging role: kB = row in k (0..31), qB = float4 slot (0..7)
    const int kB = tid >> 3, qB = tid & 7;

    for (int k0 = 0; k0 < 2 * D; k0 += BK) {
        // ---- global loads into registers ----
        float4 av0, av1;
        if (LEAF) {
            long tok = (k0 < D) ? tokL : tokR;
            const float* base = emb + tok * (long)D + (k0 & (D - 1));
            av0 = *(const float4*)(base + tA * 8);
            av1 = *(const float4*)(base + tA * 8 + 4);
        } else {
            av0 = *(const float4*)(arow + k0 + tA * 8);
            av1 = *(const float4*)(arow + k0 + tA * 8 + 4);
        }
        float4 bv[5];
#pragma unroll
        for (int g = 0; g < 5; g++) {
            const float* src = (g < 3)
                ? (W_iou + (long)(k0 + kB) * 1536 + g * D + j0 + qB * 4)
                : (W_f   + (long)(k0 + kB) * 1024 + (g - 3) * D + j0 + qB * 4);
            bv[g] = *(const float4*)src;
        }

        __syncthreads();   // previous iter's LDS reads complete

        // ---- LDS stores ----
        {
            const float* avf = (const float*)&av0;   // av0,av1 adjacent on stack
            float tmp[8] = {av0.x, av0.y, av0.z, av0.w, av1.x, av1.y, av1.z, av1.w};
            (void)avf;
#pragma unroll
            for (int u = 0; u < 8; u++)
                As[tA * 8 + u][rA] = tmp[u];
        }
#pragma unroll
        for (int g = 0; g < 5; g++)
            *(float4*)&Bs[kB][g * 32 + qB * 4] = bv[g];

        __syncthreads();

        // ---- inner product ----
#pragma unroll
        for (int kk = 0; kk < BK; kk++) {
            float b[5];
#pragma unroll
            for (int g = 0; g < 5; g++) b[g] = Bs[kk][g * 32 + tx];
            float4 a0 = *(const float4*)&As[kk][ty * 8];
            float4 a1 = *(const float4*)&As[kk][ty * 8 + 4];
            float a[8] = {a0.x, a0.y, a0.z, a0.w, a1.x, a1.y, a1.z, a1.w};
#pragma unroll
            for (int r = 0; r < 8; r++)
#pragma unroll
                for (int g = 0; g < 5; g++)
                    acc[r][g] = fmaf(a[r], b[g], acc[r][g]);
        }
    }

    // ---- fused LSTM epilogue ----
    const int j = j0 + tx;
    const float bi  = b_iou[j];
    const float bo  = b_iou[D + j];
    const float bu  = b_iou[2 * D + j];
    const float bfl = b_f[j];
    const float bfr = b_f[D + j];

#pragma unroll
    for (int r = 0; r < 8; r++) {
        const int m  = m0 + ty * 8 + r;
        const int b_ = m >> lgnp;
        const int p  = m & (np - 1);
        float i = acc[r][0] + bi;
        float o = acc[r][1] + bo;
        float u = acc[r][2] + bu;
        float fl = sigmoidf_(acc[r][3] + bfl);
        float fr = sigmoidf_(acc[r][4] + bfr);
        float cl = 0.f, cr = 0.f;
        if (!LEAF) {
            long cbase = ((long)(b_ * nc + 2 * p)) * D;
            cl = Cc[cbase + j];
            cr = Cc[cbase + D + j];
        }
        float cn = sigmoidf_(i) * tanhf(u) + fl * cl + fr * cr;
        float hn = sigmoidf_(o) * tanhf(cn);
        long pbase = ((long)(b_ * np + p)) * D;
        Hp[pbase + j] = hn;
        Cp[pbase + j] = cn;
    }
}

// out[b][c] = sum_d Hroot[b][0][d] * W_out[d][c], c in {0,1}
__global__ __launch_bounds__(256)
void out_kernel(const float* __restrict__ Hroot, const float* __restrict__ W_out,
                float* __restrict__ out)
{
    const int b = blockIdx.x;
    const int tid = threadIdx.x;
    float s0 = 0.f, s1 = 0.f;
    for (int d = tid; d < D; d += 256) {
        float h = Hroot[(long)b * D + d];
        s0 = fmaf(h, W_out[d * 2 + 0], s0);
        s1 = fmaf(h, W_out[d * 2 + 1], s1);
    }
#pragma unroll
    for (int off = 32; off > 0; off >>= 1) {
        s0 += __shfl_down(s0, off, 64);
        s1 += __shfl_down(s1, off, 64);
    }
    __shared__ float red[2][4];
    const int wave = tid >> 6;
    if ((tid & 63) == 0) { red[0][wave] = s0; red[1][wave] = s1; }
    __syncthreads();
    if (tid == 0) {
        float t0 = 0.f, t1 = 0.f;
#pragma unroll
        for (int w = 0; w < 4; w++) { t0 += red[0][w]; t1 += red[1][w]; }
        out[b * 2 + 0] = t0;
        out[b * 2 + 1] = t1;
    }
}

extern "C" void kernel_launch(void* const* d_in, const int* in_sizes, int n_in,
                              void* d_out, int out_size, void* d_ws, size_t ws_size,
                              hipStream_t stream)
{
    const int*   tokens = (const int*)  d_in[0];
    const float* emb    = (const float*)d_in[1];
    const float* W_iou  = (const float*)d_in[2];
    const float* b_iou  = (const float*)d_in[3];
    const float* W_f    = (const float*)d_in[4];
    const float* b_f    = (const float*)d_in[5];
    const float* W_out  = (const float*)d_in[6];
    float* out = (float*)d_out;

    // ping-pong state buffers in d_ws:
    //   buf0: 512 nodes (H0,C0), buf1: 256 nodes (H1,C1). Total 192 MiB.
    const long n512 = (long)512 * 64 * D;
    const long n256 = (long)256 * 64 * D;
    float* H0 = (float*)d_ws;
    float* C0 = H0 + n512;
    float* H1 = C0 + n512;
    float* C1 = H1 + n256;

    // Level 9 (leaves -> 512 parents): A gathered from embedding, c_children = 0
    {
        dim3 grid(512, 16);
        level_kernel<true><<<grid, 256, 0, stream>>>(
            nullptr, nullptr, tokens, emb, W_iou, b_iou, W_f, b_f, H0, C0, 512, 9);
    }

    float* Hc = H0; float* Cc = C0;
    float* Hp = H1; float* Cp = C1;
    for (int L = 8; L >= 0; L--) {
        const int np = 1 << L;
        dim3 grid(np, 16);
        level_kernel<false><<<grid, 256, 0, stream>>>(
            Hc, Cc, nullptr, nullptr, W_iou, b_iou, W_f, b_f, Hp, Cp, np, L);
        float* tH = Hc; float* tC = Cc;
        Hc = Hp; Cc = Cp; Hp = tH; Cp = tC;
    }

    // root h now in Hc (layout [64][1][512])
    out_kernel<<<64, 256, 0, stream>>>(Hc, W_out, out);
}

// Round 2
// 3490.857 us; speedup vs baseline: 1.9102x; 1.9102x over previous
//
#include <hip/hip_runtime.h>
#include <math.h>

typedef unsigned short u16;
typedef short s16x8 __attribute__((ext_vector_type(8)));
typedef float f32x4 __attribute__((ext_vector_type(4)));

#define KDIM 1024
#define BM 128
#define BK 32
#define AST 40      // shorts per A-LDS row: 32 k + 8 pad (80 B, spreads quad-banks)
#define BST 40

// Pre-split, transposed weights: layout [kb 32][gate 5][j 512][k 32]
__device__ __align__(16) u16 g_Bhi[1024 * 2560];
__device__ __align__(16) u16 g_Blo[1024 * 2560];

__device__ __forceinline__ u16 f2bf(float x) {
    unsigned u = __float_as_uint(x);
    u += 0x7fffu + ((u >> 16) & 1u);       // RNE
    return (u16)(u >> 16);
}
__device__ __forceinline__ float bf2f(u16 h) { return __uint_as_float(((unsigned)h) << 16); }
__device__ __forceinline__ float sigm(float x) { return 1.0f / (1.0f + expf(-x)); }
__device__ __forceinline__ unsigned pk(u16 a, u16 b) { return (unsigned)a | ((unsigned)b << 16); }

// ---------------- weight split+transpose: W[k][col] f32 -> [kb][g][j][k] bf16 hi/lo ----------
__global__ __launch_bounds__(256)
void wsplit_kernel(const float* __restrict__ Wiou, const float* __restrict__ Wf)
{
    __shared__ float tile[32][65];
    const int kb = blockIdx.x;           // 0..31
    const int cb = blockIdx.y;           // 0..39
    const int t  = threadIdx.x;
    const int c0 = cb * 64;

    {   // load 32k x 64c, coalesced on cols
        const int kk  = t >> 3;          // 0..31
        const int cu0 = (t & 7) * 8;     // 0..56
        const int k   = kb * 32 + kk;
#pragma unroll
        for (int u = 0; u < 8; u++) {
            int c = c0 + cu0 + u;
            float v = (c < 1536) ? Wiou[(size_t)k * 1536 + c]
                                 : Wf[(size_t)k * 1024 + (c - 1536)];
            tile[kk][cu0 + u] = v;
        }
    }
    __syncthreads();
    {   // write transposed, split, coalesced on dest
        const int jl = t >> 2;           // 0..63
        const int kc = (t & 3) * 8;      // 0,8,16,24
        const int g  = c0 >> 9;
        const int j  = (c0 & 511) + jl;
        size_t dst = (((size_t)kb * 5 + g) * 512 + j) * 32 + kc;
        unsigned ph[4], pl[4];
#pragma unroll
        for (int u = 0; u < 4; u++) {
            float v0 = tile[kc + 2 * u][jl];
            float v1 = tile[kc + 2 * u + 1][jl];
            u16 h0 = f2bf(v0), h1 = f2bf(v1);
            u16 l0 = f2bf(v0 - bf2f(h0)), l1 = f2bf(v1 - bf2f(h1));
            ph[u] = pk(h0, h1);
            pl[u] = pk(l0, l1);
        }
        *(uint4*)(g_Bhi + dst) = make_uint4(ph[0], ph[1], ph[2], ph[3]);
        *(uint4*)(g_Blo + dst) = make_uint4(pl[0], pl[1], pl[2], pl[3]);
    }
}

// ---------------- one tree level: split-bf16 MFMA GEMM + fused LSTM epilogue ----------------
// H layout: per row (b*n + p): 1024 u16 = 32 chunks x {16 hi, 16 lo}  (chunk q covers d = q*16..+15)
// A-row = concat(left child row, right child row) = 2048 u16 = 64 chunks, k = chunk*16 + lane
// C layout: f32 [row][512]
template<bool LEAF>
__global__ __launch_bounds__(256, 2)
void level_mfma(const u16* __restrict__ Hc, const float* __restrict__ Cc,
                const int* __restrict__ tokens, const float* __restrict__ emb,
                const float* __restrict__ b_iou, const float* __restrict__ b_f,
                u16* __restrict__ Hp, float* __restrict__ Cp,
                int np, int lgnp)
{
    __shared__ __align__(16) u16 Ah[BM * AST];
    __shared__ __align__(16) u16 Al[BM * AST];
    __shared__ __align__(16) u16 Bh[320 * BST];
    __shared__ __align__(16) u16 Bl[320 * BST];

    const int tid = threadIdx.x;
    const int jg  = blockIdx.x;          // 0..7  -> XCD via %8 round-robin
    const int m0  = blockIdx.y * BM;
    const int j0  = jg * 64;
    const int nc  = np * 2;
    const int M   = np * 64;

    // wave compute roles
    const int w    = tid >> 6;
    const int lane = tid & 63;
    const int il   = lane & 15;
    const int kq   = lane >> 4;
    const int wrow = (w & 1) * 64;       // waves 0,2 rows 0-63; 1,3 rows 64-127
    const int wjq  = (w >> 1) * 2;       // waves 0,1 jq 0-1;  2,3 jq 2-3

    f32x4 acc[4][5][2];
#pragma unroll
    for (int mf = 0; mf < 4; mf++)
#pragma unroll
        for (int g = 0; g < 5; g++)
#pragma unroll
            for (int q = 0; q < 2; q++) acc[mf][g][q] = (f32x4)0.0f;

    // A staging role: row rA, k-half tA (16 k each)
    const int rA = tid & 127;
    const int tA = tid >> 7;
    int mA = m0 + rA; if (mA > M - 1) mA = M - 1;
    const int bA = mA >> lgnp;
    const int pA = mA & (np - 1);

    const u16* arow = nullptr;
    const float *erowL = nullptr, *erowR = nullptr;
    if (LEAF) {
        int tl = tokens[bA * 1024 + 2 * pA];
        int tr = tokens[bA * 1024 + 2 * pA + 1];
        erowL = emb + (size_t)tl * 512;
        erowR = emb + (size_t)tr * 512;
    } else {
        arow = Hc + ((size_t)bA * nc + 2 * pA) * 1024;   // 2048 shorts
    }

    // B staging role
    const int jl = tid >> 2;             // 0..63
    const int kc = tid & 3;              // k chunk-of-8

    for (int k0 = 0; k0 < KDIM; k0 += BK) {
        // ---- global loads into registers ----
        uint4 a0, a1, a2, a3;
        if (LEAF) {
            const float* base = ((k0 < 512) ? erowL : erowR) + (k0 & 511) + tA * 16;
            float4 f0 = *(const float4*)(base);
            float4 f1 = *(const float4*)(base + 4);
            float4 f2 = *(const float4*)(base + 8);
            float4 f3 = *(const float4*)(base + 12);
            float v[16] = {f0.x,f0.y,f0.z,f0.w, f1.x,f1.y,f1.z,f1.w,
                           f2.x,f2.y,f2.z,f2.w, f3.x,f3.y,f3.z,f3.w};
            unsigned ph[8], pl[8];
#pragma unroll
            for (int i = 0; i < 8; i++) {
                u16 h0 = f2bf(v[2*i]),   h1 = f2bf(v[2*i+1]);
                u16 l0 = f2bf(v[2*i]   - bf2f(h0));
                u16 l1 = f2bf(v[2*i+1] - bf2f(h1));
                ph[i] = pk(h0, h1);
                pl[i] = pk(l0, l1);
            }
            a0 = make_uint4(ph[0], ph[1], ph[2], ph[3]);
            a1 = make_uint4(ph[4], ph[5], ph[6], ph[7]);
            a2 = make_uint4(pl[0], pl[1], pl[2], pl[3]);
            a3 = make_uint4(pl[4], pl[5], pl[6], pl[7]);
        } else {
            const uint4* src = (const uint4*)(arow + ((k0 >> 4) + tA) * 32);
            a0 = src[0]; a1 = src[1]; a2 = src[2]; a3 = src[3];
        }
        uint4 bhr[5], blr[5];
        const int kb = k0 >> 5;
#pragma unroll
        for (int g = 0; g < 5; g++) {
            size_t off = (((size_t)kb * 5 + g) * 512 + (j0 + jl)) * 32 + kc * 8;
            bhr[g] = *(const uint4*)(g_Bhi + off);
            blr[g] = *(const uint4*)(g_Blo + off);
        }

        __syncthreads();   // previous iter's LDS reads complete

        {   // ---- LDS stores ----
            const int ab = rA * AST + tA * 16;
            *(uint4*)&Ah[ab]     = a0;  *(uint4*)&Ah[ab + 8] = a1;
            *(uint4*)&Al[ab]     = a2;  *(uint4*)&Al[ab + 8] = a3;
        }
#pragma unroll
        for (int g = 0; g < 5; g++) {
            const int bb = (g * 64 + jl) * BST + kc * 8;
            *(uint4*)&Bh[bb] = bhr[g];
            *(uint4*)&Bl[bb] = blr[g];
        }

        __syncthreads();

        // ---- MFMA inner loop ----
        s16x8 ah[4], alr[4];
#pragma unroll
        for (int mf = 0; mf < 4; mf++) {
            const int ao = (wrow + mf * 16 + il) * AST + kq * 8;
            ah[mf]  = *(const s16x8*)&Ah[ao];
            alr[mf] = *(const s16x8*)&Al[ao];
        }
#pragma unroll
        for (int g = 0; g < 5; g++) {
#pragma unroll
            for (int q = 0; q < 2; q++) {
                const int col = g * 64 + (wjq + q) * 16 + il;
                const int bo  = col * BST + kq * 8;
                s16x8 bh = *(const s16x8*)&Bh[bo];
                s16x8 bl = *(const s16x8*)&Bl[bo];
#pragma unroll
                for (int mf = 0; mf < 4; mf++) {
                    acc[mf][g][q] = __builtin_amdgcn_mfma_f32_16x16x32_bf16(ah[mf],  bh, acc[mf][g][q], 0, 0, 0);
                    acc[mf][g][q] = __builtin_amdgcn_mfma_f32_16x16x32_bf16(ah[mf],  bl, acc[mf][g][q], 0, 0, 0);
                    acc[mf][g][q] = __builtin_amdgcn_mfma_f32_16x16x32_bf16(alr[mf], bh, acc[mf][g][q], 0, 0, 0);
                }
            }
        }
    }

    // ---- fused LSTM epilogue ----
#pragma unroll
    for (int q = 0; q < 2; q++) {
        const int jq = wjq + q;
        const int jglob = j0 + jq * 16 + il;       // 0..511
        const float bi  = b_iou[jglob];
        const float bo_ = b_iou[512 + jglob];
        const float bu  = b_iou[1024 + jglob];
        const float bfl = b_f[jglob];
        const float bfr = b_f[512 + jglob];
#pragma unroll
        for (int mf = 0; mf < 4; mf++) {
#pragma unroll
            for (int r = 0; r < 4; r++) {
                const int m = m0 + wrow + mf * 16 + kq * 4 + r;
                if (m < M) {
                    const int b = m >> lgnp;
                    const int p = m & (np - 1);
                    float i_ = acc[mf][0][q][r] + bi;
                    float o_ = acc[mf][1][q][r] + bo_;
                    float u_ = acc[mf][2][q][r] + bu;
                    float fl = sigm(acc[mf][3][q][r] + bfl);
                    float fr = sigm(acc[mf][4][q][r] + bfr);
                    float cl = 0.0f, cr = 0.0f;
                    if (!LEAF) {
                        size_t cb_ = ((size_t)b * nc + 2 * p) * 512 + jglob;
                        cl = Cc[cb_];
                        cr = Cc[cb_ + 512];
                    }
                    float cn = sigm(i_) * tanhf(u_) + fl * cl + fr * cr;
                    float hn = sigm(o_) * tanhf(cn);
                    size_t prow = (size_t)b * np + p;
                    u16 hh = f2bf(hn);
                    u16 hl = f2bf(hn - bf2f(hh));
                    Hp[prow * 1024 + (size_t)(jg * 4 + jq) * 32 + il]      = hh;
                    Hp[prow * 1024 + (size_t)(jg * 4 + jq) * 32 + 16 + il] = hl;
                    Cp[prow * 512 + jglob] = cn;
                }
            }
        }
    }
}

// ---------------- out[b][c] = sum_d h_root[b][d] * W_out[d][c] ----------------
__global__ __launch_bounds__(256)
void out_kernel(const u16* __restrict__ Hroot, const float* __restrict__ W_out,
                float* __restrict__ out)
{
    const int b = blockIdx.x;
    const int tid = threadIdx.x;
    float s0 = 0.f, s1 = 0.f;
    for (int d = tid; d < 512; d += 256) {
        const u16* row = Hroot + (size_t)b * 1024 + (d >> 4) * 32 + (d & 15);
        float h = bf2f(row[0]) + bf2f(row[16]);
        s0 = fmaf(h, W_out[d * 2 + 0], s0);
        s1 = fmaf(h, W_out[d * 2 + 1], s1);
    }
#pragma unroll
    for (int off = 32; off > 0; off >>= 1) {
        s0 += __shfl_down(s0, off, 64);
        s1 += __shfl_down(s1, off, 64);
    }
    __shared__ float red[2][4];
    const int wave = tid >> 6;
    if ((tid & 63) == 0) { red[0][wave] = s0; red[1][wave] = s1; }
    __syncthreads();
    if (tid == 0) {
        float t0 = 0.f, t1 = 0.f;
#pragma unroll
        for (int wv = 0; wv < 4; wv++) { t0 += red[0][wv]; t1 += red[1][wv]; }
        out[b * 2 + 0] = t0;
        out[b * 2 + 1] = t1;
    }
}

extern "C" void kernel_launch(void* const* d_in, const int* in_sizes, int n_in,
                              void* d_out, int out_size, void* d_ws, size_t ws_size,
                              hipStream_t stream)
{
    const int*   tokens = (const int*)  d_in[0];
    const float* emb    = (const float*)d_in[1];
    const float* W_iou  = (const float*)d_in[2];
    const float* b_iou  = (const float*)d_in[3];
    const float* W_f    = (const float*)d_in[4];
    const float* b_f    = (const float*)d_in[5];
    const float* W_out  = (const float*)d_in[6];
    float* out = (float*)d_out;

    // ws layout (201.3 MB, same total as proven round-1 usage):
    //   H0: 512-node split H (u16, 2 KB/row)   = 67.1 MB
    //   C0: 512-node C (f32)                   = 67.1 MB
    //   H1: 256-node split H                   = 33.55 MB
    //   C1: 256-node C                         = 33.55 MB
    u16*   H0 = (u16*)d_ws;
    float* C0 = (float*)(H0 + (size_t)512 * 64 * 1024);
    u16*   H1 = (u16*)(C0 + (size_t)512 * 64 * 512);
    float* C1 = (float*)(H1 + (size_t)256 * 64 * 1024);

    // one-time (per call) weight split+transpose into __device__ buffers
    wsplit_kernel<<<dim3(32, 40), 256, 0, stream>>>(W_iou, W_f);

    // level 9: leaves -> 512 parents (A gathered+split from embedding, c=0)
    level_mfma<true><<<dim3(8, 256), 256, 0, stream>>>(
        nullptr, nullptr, tokens, emb, b_iou, b_f, H0, C0, 512, 9);

    u16* Hc = H0;  float* Cc = C0;
    u16* Hp = H1;  float* Cp = C1;
    for (int L = 8; L >= 0; L--) {
        const int np = 1 << L;
        const int gy = (np * 64 + BM - 1) / BM;
        level_mfma<false><<<dim3(8, gy), 256, 0, stream>>>(
            Hc, Cc, nullptr, nullptr, b_iou, b_f, Hp, Cp, np, L);
        u16* tH = Hc; Hc = Hp; Hp = tH;
        float* tC = Cc; Cc = Cp; Cp = tC;
    }

    out_kernel<<<64, 256, 0, stream>>>(Hc, W_out, out);
}

// Round 3
// 1370.934 us; speedup vs baseline: 4.8639x; 2.5463x over previous
//
#include <hip/hip_runtime.h>
#include <math.h>

typedef unsigned short u16;
typedef short s16x8 __attribute__((ext_vector_type(8)));
typedef float f32x4 __attribute__((ext_vector_type(4)));

#define AST 40
#define BST 40
#define NITER 32   // K=1024 / BK=32

// Pre-split, transposed weights: layout [kb 32][gate 5][j 512][k 32]
__device__ __align__(16) u16 g_Bhi[1024 * 2560];
__device__ __align__(16) u16 g_Blo[1024 * 2560];

__device__ __forceinline__ u16 f2bf(float x) {
    unsigned u = __float_as_uint(x);
    u += 0x7fffu + ((u >> 16) & 1u);       // RNE
    return (u16)(u >> 16);
}
__device__ __forceinline__ float bf2f(u16 h) { return __uint_as_float(((unsigned)h) << 16); }
__device__ __forceinline__ float sigm(float x) { return 1.0f / (1.0f + expf(-x)); }
__device__ __forceinline__ unsigned pk(u16 a, u16 b) { return (unsigned)a | ((unsigned)b << 16); }

// ---------------- weight split+transpose: W[k][col] f32 -> [kb][g][j][k] bf16 hi/lo ----------
__global__ __launch_bounds__(256)
void wsplit_kernel(const float* __restrict__ Wiou, const float* __restrict__ Wf)
{
    __shared__ float tile[32][65];
    const int kb = blockIdx.x;           // 0..31
    const int cb = blockIdx.y;           // 0..39
    const int t  = threadIdx.x;
    const int c0 = cb * 64;

    {   // load 32k x 64c, coalesced on cols
        const int kk  = t >> 3;          // 0..31
        const int cu0 = (t & 7) * 8;     // 0..56
        const int k   = kb * 32 + kk;
#pragma unroll
        for (int u = 0; u < 8; u++) {
            int c = c0 + cu0 + u;
            float v = (c < 1536) ? Wiou[(size_t)k * 1536 + c]
                                 : Wf[(size_t)k * 1024 + (c - 1536)];
            tile[kk][cu0 + u] = v;
        }
    }
    __syncthreads();
    {   // write transposed, split, coalesced on dest
        const int jl = t >> 2;           // 0..63
        const int kc = (t & 3) * 8;      // 0,8,16,24
        const int g  = c0 >> 9;
        const int j  = (c0 & 511) + jl;
        size_t dst = (((size_t)kb * 5 + g) * 512 + j) * 32 + kc;
        unsigned ph[4], pl[4];
#pragma unroll
        for (int u = 0; u < 4; u++) {
            float v0 = tile[kc + 2 * u][jl];
            float v1 = tile[kc + 2 * u + 1][jl];
            u16 h0 = f2bf(v0), h1 = f2bf(v1);
            u16 l0 = f2bf(v0 - bf2f(h0)), l1 = f2bf(v1 - bf2f(h1));
            ph[u] = pk(h0, h1);
            pl[u] = pk(l0, l1);
        }
        *(uint4*)(g_Bhi + dst) = make_uint4(ph[0], ph[1], ph[2], ph[3]);
        *(uint4*)(g_Blo + dst) = make_uint4(pl[0], pl[1], pl[2], pl[3]);
    }
}

// ---------------- one tree level: split-bf16 MFMA GEMM + fused LSTM epilogue ----------------
// H layout: per row: 1024 u16 = 32 chunks x {16 hi, 16 lo}. A-row = left||right = 2048 u16 contiguous.
// C layout: f32 [row][512].
// Pipeline: double-buffered LDS, T14 split (issue loads -> compute -> ds_write -> barrier).
template<bool LEAF>
__global__ __launch_bounds__(512, 2)
void level_mfma(const u16* __restrict__ Hc, const float* __restrict__ Cc,
                const int* __restrict__ tokens, const float* __restrict__ emb,
                const float* __restrict__ b_iou, const float* __restrict__ b_f,
                u16* __restrict__ Hp, float* __restrict__ Cp,
                int np, int lgnp)
{
    __shared__ __align__(16) u16 AhL[2][128 * AST];
    __shared__ __align__(16) u16 AlL[2][128 * AST];
    __shared__ __align__(16) u16 BhL[2][320 * BST];
    __shared__ __align__(16) u16 BlL[2][320 * BST];

    const int tid = threadIdx.x;
    const int jg  = blockIdx.x;          // 0..7 -> XCD pinning via %8
    const int m0  = blockIdx.y * 128;
    const int j0  = jg * 64;
    const int nc  = np * 2;
    const int M   = np * 64;

    // wave compute roles: 8 waves = 2 (rows) x 4 (col groups)
    const int w    = tid >> 6;
    const int lane = tid & 63;
    const int il   = lane & 15;
    const int kq   = lane >> 4;
    const int wm   = w & 1;              // row half: rows wm*64 .. +63
    const int wc   = w >> 1;             // col group: j sub-range wc*16 .. +15

    f32x4 acc[4][5];                     // [rowfrag][gate]
#pragma unroll
    for (int rf = 0; rf < 4; rf++)
#pragma unroll
        for (int g = 0; g < 5; g++) acc[rf][g] = (f32x4)0.0f;

    // ---- A staging role: row rA (0..127), 32B-slot qA (0..3) ----
    const int rA = tid >> 2;
    const int qA = tid & 3;
    int mA = m0 + rA; if (mA > M - 1) mA = M - 1;
    const int bA = mA >> lgnp;
    const int pA = mA & (np - 1);

    const u16* arow = nullptr;
    const float *erowL = nullptr, *erowR = nullptr;
    if (LEAF) {
        int tl = tokens[bA * 1024 + 2 * pA];
        int tr = tokens[bA * 1024 + 2 * pA + 1];
        erowL = emb + (size_t)tl * 512;
        erowR = emb + (size_t)tr * 512;
    } else {
        arow = Hc + ((size_t)bA * nc + 2 * pA) * 1024;   // 2048 u16, contiguous pair
    }

    // ---- B staging role: hi/lo half, col cr (0..63), 16B-slot s (0..3) ----
    const int hl = tid >> 8;             // wave-uniform
    const int cr = (tid >> 2) & 63;
    const int sB = tid & 3;
    const u16* bsrc = hl ? g_Blo : g_Bhi;

    // staging registers (tile t+1 in flight during compute of t)
    uint4  aR0, aR1;
    float4 fR0, fR1;
    uint4  bR[5];

    // ================= load tile t into regs =================
#define LOAD_TILE(t_)                                                          \
    {                                                                          \
        const int t__ = (t_);                                                  \
        if (LEAF) {                                                            \
            const float* asrc = ((t__ < 16) ? erowL : erowR)                   \
                                + ((32 * t__) & 511) + qA * 8;                 \
            fR0 = *(const float4*)asrc;                                        \
            fR1 = *(const float4*)(asrc + 4);                                  \
        } else {                                                               \
            const u16* asrc = arow + t__ * 64 + qA * 16;                       \
            aR0 = *(const uint4*)asrc;                                         \
            aR1 = *(const uint4*)(asrc + 8);                                   \
        }                                                                      \
        _Pragma("unroll")                                                      \
        for (int g = 0; g < 5; g++) {                                          \
            size_t off = (((size_t)t__ * 5 + g) * 512 + j0 + cr) * 32 + sB * 8;\
            bR[g] = *(const uint4*)(bsrc + off);                               \
        }                                                                      \
    }

    // ================= write regs into LDS buffer bf =================
#define WRITE_TILE(bf)                                                         \
    {                                                                          \
        const int bf__ = (bf);                                                 \
        if (LEAF) {                                                            \
            float v[8] = {fR0.x, fR0.y, fR0.z, fR0.w, fR1.x, fR1.y, fR1.z, fR1.w}; \
            unsigned ph[4], pl[4];                                             \
            _Pragma("unroll")                                                  \
            for (int i = 0; i < 4; i++) {                                      \
                u16 h0 = f2bf(v[2 * i]), h1 = f2bf(v[2 * i + 1]);              \
                u16 l0 = f2bf(v[2 * i] - bf2f(h0));                            \
                u16 l1 = f2bf(v[2 * i + 1] - bf2f(h1));                        \
                ph[i] = pk(h0, h1);  pl[i] = pk(l0, l1);                       \
            }                                                                  \
            *(uint4*)&AhL[bf__][rA * AST + qA * 8] = make_uint4(ph[0], ph[1], ph[2], ph[3]); \
            *(uint4*)&AlL[bf__][rA * AST + qA * 8] = make_uint4(pl[0], pl[1], pl[2], pl[3]); \
        } else {                                                               \
            const int part = qA & 1, khalf = qA >> 1;                          \
            u16* dst = (part ? AlL[bf__] : AhL[bf__]) + rA * AST + khalf * 16; \
            *(uint4*)dst       = aR0;                                          \
            *(uint4*)(dst + 8) = aR1;                                          \
        }                                                                      \
        {                                                                      \
            u16* bdst = (hl ? BlL[bf__] : BhL[bf__]);                          \
            _Pragma("unroll")                                                  \
            for (int g = 0; g < 5; g++)                                        \
                *(uint4*)&bdst[(g * 64 + cr) * BST + sB * 8] = bR[g];          \
        }                                                                      \
    }

    // ================= prologue =================
    LOAD_TILE(0);
    WRITE_TILE(0);
    __syncthreads();

    int cur = 0;
    for (int t = 0; t < NITER; ++t) {
        const bool more = (t + 1 < NITER);
        if (more) LOAD_TILE(t + 1);       // issue global loads (in flight during compute)

        // ---- compute tile t from buf[cur] ----
        {
            const u16* Ahc = AhL[cur];
            const u16* Alc = AlL[cur];
            const u16* Bhc = BhL[cur];
            const u16* Blc = BlL[cur];
            s16x8 ahv[4], alv[4];
#pragma unroll
            for (int rf = 0; rf < 4; rf++) {
                const int ao = (wm * 64 + rf * 16 + il) * AST + kq * 8;
                ahv[rf] = *(const s16x8*)&Ahc[ao];
                alv[rf] = *(const s16x8*)&Alc[ao];
            }
#pragma unroll
            for (int g = 0; g < 5; g++) {
                const int bo = (g * 64 + wc * 16 + il) * BST + kq * 8;
                s16x8 bhv = *(const s16x8*)&Bhc[bo];
                s16x8 blv = *(const s16x8*)&Blc[bo];
#pragma unroll
                for (int rf = 0; rf < 4; rf++) {
                    acc[rf][g] = __builtin_amdgcn_mfma_f32_16x16x32_bf16(ahv[rf], bhv, acc[rf][g], 0, 0, 0);
                    acc[rf][g] = __builtin_amdgcn_mfma_f32_16x16x32_bf16(ahv[rf], blv, acc[rf][g], 0, 0, 0);
                    acc[rf][g] = __builtin_amdgcn_mfma_f32_16x16x32_bf16(alv[rf], bhv, acc[rf][g], 0, 0, 0);
                }
            }
        }

        if (more) {
            WRITE_TILE(cur ^ 1);          // vmcnt waits land here, after compute
            __syncthreads();
            cur ^= 1;
        }
    }
#undef LOAD_TILE
#undef WRITE_TILE

    // ================= fused LSTM epilogue =================
    const int jglob = j0 + wc * 16 + il;       // 0..511
    const float bi  = b_iou[jglob];
    const float bo_ = b_iou[512 + jglob];
    const float bu  = b_iou[1024 + jglob];
    const float bfl = b_f[jglob];
    const float bfr = b_f[512 + jglob];

#pragma unroll
    for (int rf = 0; rf < 4; rf++) {
#pragma unroll
        for (int r = 0; r < 4; r++) {
            const int m = m0 + wm * 64 + rf * 16 + kq * 4 + r;
            if (m < M) {
                const int b = m >> lgnp;
                const int p = m & (np - 1);
                float i_ = acc[rf][0][r] + bi;
                float o_ = acc[rf][1][r] + bo_;
                float u_ = acc[rf][2][r] + bu;
                float fl = sigm(acc[rf][3][r] + bfl);
                float fr = sigm(acc[rf][4][r] + bfr);
                float cl = 0.0f, cr_ = 0.0f;
                if (!LEAF) {
                    size_t cb_ = ((size_t)b * nc + 2 * p) * 512 + jglob;
                    cl  = Cc[cb_];
                    cr_ = Cc[cb_ + 512];
                }
                float cn = sigm(i_) * tanhf(u_) + fl * cl + fr * cr_;
                float hn = sigm(o_) * tanhf(cn);
                size_t prow = (size_t)b * np + p;
                u16 hh = f2bf(hn);
                u16 hlo = f2bf(hn - bf2f(hh));
                Hp[prow * 1024 + (size_t)(jg * 4 + wc) * 32 + il]      = hh;
                Hp[prow * 1024 + (size_t)(jg * 4 + wc) * 32 + 16 + il] = hlo;
                Cp[prow * 512 + jglob] = cn;
            }
        }
    }
}

// ---------------- out[b][c] = sum_d h_root[b][d] * W_out[d][c] ----------------
__global__ __launch_bounds__(256)
void out_kernel(const u16* __restrict__ Hroot, const float* __restrict__ W_out,
                float* __restrict__ out)
{
    const int b = blockIdx.x;
    const int tid = threadIdx.x;
    float s0 = 0.f, s1 = 0.f;
    for (int d = tid; d < 512; d += 256) {
        const u16* row = Hroot + (size_t)b * 1024 + (d >> 4) * 32 + (d & 15);
        float h = bf2f(row[0]) + bf2f(row[16]);
        s0 = fmaf(h, W_out[d * 2 + 0], s0);
        s1 = fmaf(h, W_out[d * 2 + 1], s1);
    }
#pragma unroll
    for (int off = 32; off > 0; off >>= 1) {
        s0 += __shfl_down(s0, off, 64);
        s1 += __shfl_down(s1, off, 64);
    }
    __shared__ float red[2][4];
    const int wave = tid >> 6;
    if ((tid & 63) == 0) { red[0][wave] = s0; red[1][wave] = s1; }
    __syncthreads();
    if (tid == 0) {
        float t0 = 0.f, t1 = 0.f;
#pragma unroll
        for (int wv = 0; wv < 4; wv++) { t0 += red[0][wv]; t1 += red[1][wv]; }
        out[b * 2 + 0] = t0;
        out[b * 2 + 1] = t1;
    }
}

extern "C" void kernel_launch(void* const* d_in, const int* in_sizes, int n_in,
                              void* d_out, int out_size, void* d_ws, size_t ws_size,
                              hipStream_t stream)
{
    const int*   tokens = (const int*)  d_in[0];
    const float* emb    = (const float*)d_in[1];
    const float* W_iou  = (const float*)d_in[2];
    const float* b_iou  = (const float*)d_in[3];
    const float* W_f    = (const float*)d_in[4];
    const float* b_f    = (const float*)d_in[5];
    const float* W_out  = (const float*)d_in[6];
    float* out = (float*)d_out;

    // ws layout (201.3 MB, proven):
    u16*   H0 = (u16*)d_ws;
    float* C0 = (float*)(H0 + (size_t)512 * 64 * 1024);
    u16*   H1 = (u16*)(C0 + (size_t)512 * 64 * 512);
    float* C1 = (float*)(H1 + (size_t)256 * 64 * 1024);

    wsplit_kernel<<<dim3(32, 40), 256, 0, stream>>>(W_iou, W_f);

    // level 9: leaves -> 512 parents
    level_mfma<true><<<dim3(8, 256), 512, 0, stream>>>(
        nullptr, nullptr, tokens, emb, b_iou, b_f, H0, C0, 512, 9);

    u16* Hc = H0;  float* Cc = C0;
    u16* Hp = H1;  float* Cp = C1;
    for (int L = 8; L >= 0; L--) {
        const int np = 1 << L;
        const int gy = (np * 64 + 127) / 128;
        level_mfma<false><<<dim3(8, gy), 512, 0, stream>>>(
            Hc, Cc, nullptr, nullptr, b_iou, b_f, Hp, Cp, np, L);
        u16* tH = Hc; Hc = Hp; Hp = tH;
        float* tC = Cc; Cc = Cp; Cp = tC;
    }

    out_kernel<<<64, 256, 0, stream>>>(Hc, W_out, out);
}

// Round 4
// 1332.739 us; speedup vs baseline: 5.0033x; 1.0287x over previous
//
#include <hip/hip_runtime.h>
#include <math.h>

typedef unsigned short u16;
typedef short s16x8 __attribute__((ext_vector_type(8)));
typedef float f32x4 __attribute__((ext_vector_type(4)));

#define NITER 32   // K=1024 / BK=32
#define ARW 72     // u16 per A LDS row: [32 hi][32 lo][8 pad] = 144 B
#define BRW 72     // u16 per B LDS col-row: same

// Pre-split, transposed weights: layout [kb 32][gate 5][j 512][k 32]
__device__ __align__(16) u16 g_Bhi[1024 * 2560];
__device__ __align__(16) u16 g_Blo[1024 * 2560];

__device__ __forceinline__ u16 f2bf(float x) {
    unsigned u = __float_as_uint(x);
    u += 0x7fffu + ((u >> 16) & 1u);       // RNE
    return (u16)(u >> 16);
}
__device__ __forceinline__ float bf2f(u16 h) { return __uint_as_float(((unsigned)h) << 16); }
__device__ __forceinline__ float sigm(float x) { return 1.0f / (1.0f + expf(-x)); }
__device__ __forceinline__ unsigned pk(u16 a, u16 b) { return (unsigned)a | ((unsigned)b << 16); }

// ---------------- weight split+transpose: W[k][col] f32 -> [kb][g][j][k] bf16 hi/lo ----------
__global__ __launch_bounds__(256)
void wsplit_kernel(const float* __restrict__ Wiou, const float* __restrict__ Wf)
{
    __shared__ float tile[32][65];
    const int kb = blockIdx.x;           // 0..31
    const int cb = blockIdx.y;           // 0..39
    const int t  = threadIdx.x;
    const int c0 = cb * 64;

    {   // load 32k x 64c, coalesced on cols
        const int kk  = t >> 3;          // 0..31
        const int cu0 = (t & 7) * 8;     // 0..56
        const int k   = kb * 32 + kk;
#pragma unroll
        for (int u = 0; u < 8; u++) {
            int c = c0 + cu0 + u;
            float v = (c < 1536) ? Wiou[(size_t)k * 1536 + c]
                                 : Wf[(size_t)k * 1024 + (c - 1536)];
            tile[kk][cu0 + u] = v;
        }
    }
    __syncthreads();
    {   // write transposed, split, coalesced on dest
        const int jl = t >> 2;           // 0..63
        const int kc = (t & 3) * 8;      // 0,8,16,24
        const int g  = c0 >> 9;
        const int j  = (c0 & 511) + jl;
        size_t dst = (((size_t)kb * 5 + g) * 512 + j) * 32 + kc;
        unsigned ph[4], pl[4];
#pragma unroll
        for (int u = 0; u < 4; u++) {
            float v0 = tile[kc + 2 * u][jl];
            float v1 = tile[kc + 2 * u + 1][jl];
            u16 h0 = f2bf(v0), h1 = f2bf(v1);
            u16 l0 = f2bf(v0 - bf2f(h0)), l1 = f2bf(v1 - bf2f(h1));
            ph[u] = pk(h0, h1);
            pl[u] = pk(l0, l1);
        }
        *(uint4*)(g_Bhi + dst) = make_uint4(ph[0], ph[1], ph[2], ph[3]);
        *(uint4*)(g_Blo + dst) = make_uint4(pl[0], pl[1], pl[2], pl[3]);
    }
}

// ---------------- one tree level: split-bf16 MFMA GEMM + fused LSTM epilogue ----------------
// H global layout: per row: 1024 u16 = 32 chunks x {16 hi, 16 lo}. A-row = left||right contiguous.
// LDS layout: combined 144B rows [32 hi][32 lo][8 pad] -> all accesses uniform <=2-way (free).
// Pipeline: double-buffered LDS, T14 split (issue loads -> compute -> ds_write -> barrier).
template<bool LEAF>
__global__ __launch_bounds__(512, 2)
void level_mfma(const u16* __restrict__ Hc, const float* __restrict__ Cc,
                const int* __restrict__ tokens, const float* __restrict__ emb,
                const float* __restrict__ b_iou, const float* __restrict__ b_f,
                u16* __restrict__ Hp, float* __restrict__ Cp,
                int np, int lgnp)
{
    __shared__ __align__(16) u16 Ac[2][128 * ARW];   // 2 x 18.4 KB
    __shared__ __align__(16) u16 Bc[2][320 * BRW];   // 2 x 46.1 KB   total 129 KB

    const int tid = threadIdx.x;
    const int jg  = blockIdx.x;          // 0..7 -> XCD pinning via %8
    const int m0  = blockIdx.y * 128;
    const int j0  = jg * 64;
    const int nc  = np * 2;
    const int M   = np * 64;

    // wave compute roles: 8 waves = 2 (row halves) x 4 (col groups)
    const int w    = tid >> 6;
    const int lane = tid & 63;
    const int il   = lane & 15;
    const int kq   = lane >> 4;
    const int wm   = w & 1;              // rows wm*64 .. +63
    const int wc   = w >> 1;             // j sub-range wc*16 .. +15

    f32x4 acc[4][5];                     // [rowfrag][gate]
#pragma unroll
    for (int rf = 0; rf < 4; rf++)
#pragma unroll
        for (int g = 0; g < 5; g++) acc[rf][g] = (f32x4)0.0f;

    // ---- A staging role: row rA (0..127), quarter qA (0..3) ----
    const int rA = tid >> 2;
    const int qA = tid & 3;
    int mA = m0 + rA; if (mA > M - 1) mA = M - 1;
    const int bA = mA >> lgnp;
    const int pA = mA & (np - 1);

    const u16* arow = nullptr;
    const float *erowL = nullptr, *erowR = nullptr;
    if (LEAF) {
        int tl = tokens[bA * 1024 + 2 * pA];
        int tr = tokens[bA * 1024 + 2 * pA + 1];
        erowL = emb + (size_t)tl * 512;
        erowR = emb + (size_t)tr * 512;
    } else {
        arow = Hc + ((size_t)bA * nc + 2 * pA) * 1024;   // 2048 u16, contiguous pair
    }
    // inner A LDS dest: chunk qA: {hi2t, lo2t, hi2t+1, lo2t+1} -> rA*72 + (qA&1)*32 + (qA>>1)*16
    const int daI = rA * ARW + (qA & 1) * 32 + (qA >> 1) * 16;
    // leaf A LDS dest: k-chunk qA*8, hi at +0, lo at +32
    const int daL = rA * ARW + qA * 8;

    // ---- B staging role: s = 16B slot (0..7), cr = j within group (0..63), g = unit 0..4 ----
    const int sB = tid & 7;
    const int cr = tid >> 3;
    const u16* bsel = (sB < 4) ? g_Bhi : g_Blo;
    const int soff = (sB & 3) * 8;
    // dest per g: (g*64+cr)*72 + (s&3)*8 + (s>>2)*32
    const int dbB = cr * BRW + soff + (sB >> 2) * 32;

    // staging registers (tile t+1 in flight during compute of t)
    uint4  aR0, aR1;
    float4 fR0, fR1;
    uint4  bR[5];

#define LOAD_TILE(t_)                                                          \
    {                                                                          \
        const int t__ = (t_);                                                  \
        if (LEAF) {                                                            \
            const float* asrc = ((t__ < 16) ? erowL : erowR)                   \
                                + ((32 * t__) & 511) + qA * 8;                 \
            fR0 = *(const float4*)asrc;                                        \
            fR1 = *(const float4*)(asrc + 4);                                  \
        } else {                                                               \
            const u16* asrc = arow + t__ * 64 + qA * 16;                       \
            aR0 = *(const uint4*)asrc;                                         \
            aR1 = *(const uint4*)(asrc + 8);                                   \
        }                                                                      \
        _Pragma("unroll")                                                      \
        for (int g = 0; g < 5; g++) {                                          \
            size_t off = (((size_t)t__ * 5 + g) * 512 + j0 + cr) * 32 + soff;  \
            bR[g] = *(const uint4*)(bsel + off);                               \
        }                                                                      \
    }

#define WRITE_TILE(bf)                                                         \
    {                                                                          \
        const int bf__ = (bf);                                                 \
        if (LEAF) {                                                            \
            float v[8] = {fR0.x, fR0.y, fR0.z, fR0.w, fR1.x, fR1.y, fR1.z, fR1.w}; \
            unsigned ph[4], pl[4];                                             \
            _Pragma("unroll")                                                  \
            for (int i = 0; i < 4; i++) {                                      \
                u16 h0 = f2bf(v[2 * i]), h1 = f2bf(v[2 * i + 1]);              \
                u16 l0 = f2bf(v[2 * i] - bf2f(h0));                            \
                u16 l1 = f2bf(v[2 * i + 1] - bf2f(h1));                        \
                ph[i] = pk(h0, h1);  pl[i] = pk(l0, l1);                       \
            }                                                                  \
            *(uint4*)&Ac[bf__][daL]      = make_uint4(ph[0], ph[1], ph[2], ph[3]); \
            *(uint4*)&Ac[bf__][daL + 32] = make_uint4(pl[0], pl[1], pl[2], pl[3]); \
        } else {                                                               \
            *(uint4*)&Ac[bf__][daI]     = aR0;                                 \
            *(uint4*)&Ac[bf__][daI + 8] = aR1;                                 \
        }                                                                      \
        _Pragma("unroll")                                                      \
        for (int g = 0; g < 5; g++)                                            \
            *(uint4*)&Bc[bf__][g * 64 * BRW + dbB] = bR[g];                    \
    }

    // ================= prologue =================
    LOAD_TILE(0);
    WRITE_TILE(0);
    __syncthreads();

    int cur = 0;
    for (int t = 0; t < NITER; ++t) {
        const bool more = (t + 1 < NITER);
        if (more) LOAD_TILE(t + 1);       // global loads in flight during compute

        // ---- compute tile t from buf[cur] ----
        {
            const u16* Acc_ = Ac[cur];
            const u16* Bcc_ = Bc[cur];
            s16x8 ahv[4], alv[4];
#pragma unroll
            for (int rf = 0; rf < 4; rf++) {
                const int ao = (wm * 64 + rf * 16 + il) * ARW + kq * 8;
                ahv[rf] = *(const s16x8*)&Acc_[ao];
                alv[rf] = *(const s16x8*)&Acc_[ao + 32];
            }
#pragma unroll
            for (int g = 0; g < 5; g++) {
                const int bo = (g * 64 + wc * 16 + il) * BRW + kq * 8;
                s16x8 bhv = *(const s16x8*)&Bcc_[bo];
                s16x8 blv = *(const s16x8*)&Bcc_[bo + 32];
#pragma unroll
                for (int rf = 0; rf < 4; rf++) {
                    acc[rf][g] = __builtin_amdgcn_mfma_f32_16x16x32_bf16(ahv[rf], bhv, acc[rf][g], 0, 0, 0);
                    acc[rf][g] = __builtin_amdgcn_mfma_f32_16x16x32_bf16(ahv[rf], blv, acc[rf][g], 0, 0, 0);
                    acc[rf][g] = __builtin_amdgcn_mfma_f32_16x16x32_bf16(alv[rf], bhv, acc[rf][g], 0, 0, 0);
                }
            }
        }

        if (more) {
            WRITE_TILE(cur ^ 1);          // vmcnt waits land here, after compute
            __syncthreads();
            cur ^= 1;
        }
    }
#undef LOAD_TILE
#undef WRITE_TILE

    // ================= fused LSTM epilogue =================
    const int jglob = j0 + wc * 16 + il;       // 0..511
    const float bi  = b_iou[jglob];
    const float bo_ = b_iou[512 + jglob];
    const float bu  = b_iou[1024 + jglob];
    const float bfl = b_f[jglob];
    const float bfr = b_f[512 + jglob];

#pragma unroll
    for (int rf = 0; rf < 4; rf++) {
#pragma unroll
        for (int r = 0; r < 4; r++) {
            const int m = m0 + wm * 64 + rf * 16 + kq * 4 + r;
            if (m < M) {
                const int b = m >> lgnp;
                const int p = m & (np - 1);
                float i_ = acc[rf][0][r] + bi;
                float o_ = acc[rf][1][r] + bo_;
                float u_ = acc[rf][2][r] + bu;
                float fl = sigm(acc[rf][3][r] + bfl);
                float fr = sigm(acc[rf][4][r] + bfr);
                float cl = 0.0f, cr_ = 0.0f;
                if (!LEAF) {
                    size_t cb_ = ((size_t)b * nc + 2 * p) * 512 + jglob;
                    cl  = Cc[cb_];
                    cr_ = Cc[cb_ + 512];
                }
                float cn = sigm(i_) * tanhf(u_) + fl * cl + fr * cr_;
                float hn = sigm(o_) * tanhf(cn);
                size_t prow = (size_t)b * np + p;
                u16 hh = f2bf(hn);
                u16 hlo = f2bf(hn - bf2f(hh));
                Hp[prow * 1024 + (size_t)(jg * 4 + wc) * 32 + il]      = hh;
                Hp[prow * 1024 + (size_t)(jg * 4 + wc) * 32 + 16 + il] = hlo;
                Cp[prow * 512 + jglob] = cn;
            }
        }
    }
}

// ---------------- out[b][c] = sum_d h_root[b][d] * W_out[d][c] ----------------
__global__ __launch_bounds__(256)
void out_kernel(const u16* __restrict__ Hroot, const float* __restrict__ W_out,
                float* __restrict__ out)
{
    const int b = blockIdx.x;
    const int tid = threadIdx.x;
    float s0 = 0.f, s1 = 0.f;
    for (int d = tid; d < 512; d += 256) {
        const u16* row = Hroot + (size_t)b * 1024 + (d >> 4) * 32 + (d & 15);
        float h = bf2f(row[0]) + bf2f(row[16]);
        s0 = fmaf(h, W_out[d * 2 + 0], s0);
        s1 = fmaf(h, W_out[d * 2 + 1], s1);
    }
#pragma unroll
    for (int off = 32; off > 0; off >>= 1) {
        s0 += __shfl_down(s0, off, 64);
        s1 += __shfl_down(s1, off, 64);
    }
    __shared__ float red[2][4];
    const int wave = tid >> 6;
    if ((tid & 63) == 0) { red[0][wave] = s0; red[1][wave] = s1; }
    __syncthreads();
    if (tid == 0) {
        float t0 = 0.f, t1 = 0.f;
#pragma unroll
        for (int wv = 0; wv < 4; wv++) { t0 += red[0][wv]; t1 += red[1][wv]; }
        out[b * 2 + 0] = t0;
        out[b * 2 + 1] = t1;
    }
}

extern "C" void kernel_launch(void* const* d_in, const int* in_sizes, int n_in,
                              void* d_out, int out_size, void* d_ws, size_t ws_size,
                              hipStream_t stream)
{
    const int*   tokens = (const int*)  d_in[0];
    const float* emb    = (const float*)d_in[1];
    const float* W_iou  = (const float*)d_in[2];
    const float* b_iou  = (const float*)d_in[3];
    const float* W_f    = (const float*)d_in[4];
    const float* b_f    = (const float*)d_in[5];
    const float* W_out  = (const float*)d_in[6];
    float* out = (float*)d_out;

    // ws layout (201.3 MB, proven):
    u16*   H0 = (u16*)d_ws;
    float* C0 = (float*)(H0 + (size_t)512 * 64 * 1024);
    u16*   H1 = (u16*)(C0 + (size_t)512 * 64 * 512);
    float* C1 = (float*)(H1 + (size_t)256 * 64 * 1024);

    wsplit_kernel<<<dim3(32, 40), 256, 0, stream>>>(W_iou, W_f);

    // level 9: leaves -> 512 parents
    level_mfma<true><<<dim3(8, 256), 512, 0, stream>>>(
        nullptr, nullptr, tokens, emb, b_iou, b_f, H0, C0, 512, 9);

    u16* Hc = H0;  float* Cc = C0;
    u16* Hp = H1;  float* Cp = C1;
    for (int L = 8; L >= 0; L--) {
        const int np = 1 << L;
        const int gy = (np * 64 + 127) / 128;
        level_mfma<false><<<dim3(8, gy), 512, 0, stream>>>(
            Hc, Cc, nullptr, nullptr, b_iou, b_f, Hp, Cp, np, L);
        u16* tH = Hc; Hc = Hp; Hp = tH;
        float* tC = Cc; Cc = Cp; Cp = tC;
    }

    out_kernel<<<64, 256, 0, stream>>>(Hc, W_out, out);
}